// Round 12
// baseline (68.277 us; speedup 1.0000x reference)
//
#include <hip/hip_runtime.h>

// VectorQuantizer, round 12: E-in-registers via fragment-ordered bf16 image.
// econv:  E fp32 -> img[8192] bf16x8 frags ordered ((w*8+tl)*2+s)*64+lane,
//         so vq_main loads A-frags with plain coalesced dwordx4 (1KB/instr).
// vq_main: grid 512 x 512 thr (8 waves/block, 128 rows/block). Wave owns a
//         128-code strip in 2 passes of 4 tiles (ea[4][2]=32 regs -- round 11
//         spilled because it loaded fp32 E for 8 tiles: 128 transient regs).
//         X staged once in 16KB swizzled LDS; inner loop: 2 ds_read_b128
//         (1-rg prefetch) + 8 MFMA (4 indep chains) + 4 SCORE4 per rowgroup.
//         amdgpu_waves_per_eu(4) caps at 128 regs (demand ~85) -> 4 waves/
//         SIMD, 2 blocks/CU. Epilogue: strip-key merge via LDS, exact fp32
//         E gather, on-the-fly ||e||^2, per-block loss partial, no atomics.
// vq_loss: 1 block sums 512 partials.

#define NROWS 65536
#define THREADS 512
#define GRID 512

using bf16x8 = __attribute__((ext_vector_type(8))) short;
using f32x4 = __attribute__((ext_vector_type(4))) float;

__device__ __forceinline__ short f2bf(float f) {  // fp32 -> bf16 RNE
  unsigned u = __float_as_uint(f);
  u += 0x7FFFu + ((u >> 16) & 1u);
  return (short)(u >> 16);
}

#define MFMA16(A, B, C) __builtin_amdgcn_mfma_f32_16x16x32_bf16((A), (B), (C), 0, 0, 0)

// kb bits (multiples of 4, <1024) disjoint from reg bits {0,1}; low 10
// mantissa bits carry k. v_and_or + max3-shaped tree.
#define SCORE4(Q, KB, KEY)                                                  \
  {                                                                         \
    const float v0 = __uint_as_float((__float_as_uint(Q[0]) & 0xFFFFFC00u) | (KB));       \
    const float v1 = __uint_as_float((__float_as_uint(Q[1]) & 0xFFFFFC00u) | ((KB) + 1)); \
    const float v2 = __uint_as_float((__float_as_uint(Q[2]) & 0xFFFFFC00u) | ((KB) + 2)); \
    const float v3 = __uint_as_float((__float_as_uint(Q[3]) & 0xFFFFFC00u) | ((KB) + 3)); \
    const float tt = fmaxf(fmaxf(v0, v1), v2);                              \
    KEY = fmaxf(fmaxf(KEY, tt), v3);                                        \
  }

// ---- E fp32 -> fragment-ordered bf16 image (once per launch) ----
__global__ __launch_bounds__(256) void econv(
    const float* __restrict__ E, bf16x8* __restrict__ img) {
  const int f = (int)blockIdx.x * 256 + threadIdx.x;  // 0..8191
  const int lane = f & 63;
  const int s = (f >> 6) & 1;
  const int tl = (f >> 7) & 7;
  const int w = f >> 10;
  const int code = w * 128 + tl * 16 + (lane & 15);
  const int fo = code * 16 + s * 8 + (lane >> 4) * 2;  // float4 units
  const float4* E4 = (const float4*)E;
  const float4 a = E4[fo];
  const float4 b = E4[fo + 1];
  bf16x8 v;
  v[0] = f2bf(a.x); v[1] = f2bf(a.y); v[2] = f2bf(a.z); v[3] = f2bf(a.w);
  v[4] = f2bf(b.x); v[5] = f2bf(b.y); v[6] = f2bf(b.z); v[7] = f2bf(b.w);
  img[f] = v;
}

__global__ __launch_bounds__(THREADS)
__attribute__((amdgpu_waves_per_eu(4))) void vq_main(
    const float* __restrict__ X, const float* __restrict__ E,
    const bf16x8* __restrict__ img, float* __restrict__ out,
    float* __restrict__ partial) {
  __shared__ short xt[128 * 64];    // 16KB bf16 X-tile, XOR-swizzled
  __shared__ float sxl[128];        // ||x||^2 per row
  __shared__ float lkeys[8][128];   // per-wave strip keys for merge
  __shared__ float wls[8];

  const int t = threadIdx.x;
  const int bid = (int)blockIdx.x;
  const int lane = t & 63;
  const int w = t >> 6;
  const int lo16 = lane & 15;
  const int khi = lane >> 4;        // 0..3
  const int rowbase = bid * 128;

  // ---- stage X: thread -> (row r = t>>2, quarter q = t&3), 16 floats ----
  {
    const int r = t >> 2, q = t & 3;
    const float4* X4 = (const float4*)X + ((size_t)(rowbase + r) * 16 + q * 4);
    const float4 a = X4[0], b = X4[1], c = X4[2], d = X4[3];
    float s = a.x * a.x + a.y * a.y + a.z * a.z + a.w * a.w
            + b.x * b.x + b.y * b.y + b.z * b.z + b.w * b.w
            + c.x * c.x + c.y * c.y + c.z * c.z + c.w * c.w
            + d.x * d.x + d.y * d.y + d.z * d.z + d.w * d.w;
    s += __shfl_xor(s, 1);
    s += __shfl_xor(s, 2);
    if (q == 0) sxl[r] = s;
    bf16x8 v, u;
    v[0] = f2bf(a.x); v[1] = f2bf(a.y); v[2] = f2bf(a.z); v[3] = f2bf(a.w);
    v[4] = f2bf(b.x); v[5] = f2bf(b.y); v[6] = f2bf(b.z); v[7] = f2bf(b.w);
    u[0] = f2bf(c.x); u[1] = f2bf(c.y); u[2] = f2bf(c.z); u[3] = f2bf(c.w);
    u[4] = f2bf(d.x); u[5] = f2bf(d.y); u[6] = f2bf(d.z); u[7] = f2bf(d.w);
    const int so = r * 64 + q * 16;
    const int sw = (r & 7) << 3;    // XOR swizzle (shorts), bits 3..5
    *(bf16x8*)&xt[so ^ sw] = v;
    *(bf16x8*)&xt[(so + 8) ^ sw] = u;
  }
  __syncthreads();

  // ---- K-loop: 2 passes of 4 code-tiles; A-frags loaded coalesced from the
  //      fragment-ordered image (no fp32 temps), B from LDS w/ 1-rg prefetch ----
  const int bsw = (lo16 & 7) << 3;
  float key[8];
#pragma unroll
  for (int rg = 0; rg < 8; ++rg) key[rg] = -INFINITY;
  const f32x4 z = {};
  bf16x8 b0, b1, n0, n1;

#define READB(B0, B1, RG)                                                   \
  {                                                                         \
    const int ro = ((RG) * 16 + lo16) * 64 + khi * 8;                       \
    B0 = *(const bf16x8*)&xt[ro ^ bsw];                                     \
    B1 = *(const bf16x8*)&xt[(ro + 32) ^ bsw];                              \
  }

#pragma unroll
  for (int pass = 0; pass < 2; ++pass) {
    bf16x8 ea[4][2];
    {
      const bf16x8* ib = img + ((w * 8 + pass * 4) * 2) * 64 + lane;
#pragma unroll
      for (int tl = 0; tl < 4; ++tl) {
        ea[tl][0] = ib[(2 * tl) * 64];
        ea[tl][1] = ib[(2 * tl + 1) * 64];
      }
    }
    const unsigned kpb = (unsigned)(w * 128 + pass * 64 + khi * 4);
    READB(b0, b1, 0)
#pragma unroll
    for (int rg = 0; rg < 8; ++rg) {
      if (rg < 7) READB(n0, n1, rg + 1)
      float kk = key[rg];
#pragma unroll
      for (int tl = 0; tl < 4; ++tl) {
        f32x4 q = MFMA16(ea[tl][0], b0, z);
        q = MFMA16(ea[tl][1], b1, q);
        SCORE4(q, kpb + (unsigned)(tl * 16), kk)
      }
      key[rg] = kk;
      b0 = n0; b1 = n1;
    }
  }
#undef READB

  // ---- reduce khi groups (same row, disjoint codes), publish strip keys ----
#pragma unroll
  for (int rg = 0; rg < 8; ++rg) {
    float kk = key[rg];
    kk = fmaxf(kk, __shfl_xor(kk, 16));
    kk = fmaxf(kk, __shfl_xor(kk, 32));
    if (khi == 0) lkeys[w][rg * 16 + lo16] = kk;
  }
  __syncthreads();

  // ---- merge 8 strips, gather EXACT fp32 E row, loss term ----
  float lt = 0.f;
  {
    const int r = t >> 2, q = t & 3;
    float m = lkeys[0][r];
    m = fmaxf(m, lkeys[1][r]); m = fmaxf(m, lkeys[2][r]);
    m = fmaxf(m, lkeys[3][r]); m = fmaxf(m, lkeys[4][r]);
    m = fmaxf(m, lkeys[5][r]); m = fmaxf(m, lkeys[6][r]);
    m = fmaxf(m, lkeys[7][r]);
    const unsigned kbu = __float_as_uint(m);
    const int k = (int)(kbu & 1023u);
    const float md = __uint_as_float(kbu & 0xFFFFFC00u);
    const float4* Ek = (const float4*)E + ((size_t)k * 16 + q * 4);
    const float4 e0 = Ek[0], e1 = Ek[1], e2 = Ek[2], e3 = Ek[3];
    float4* O4 = (float4*)out + ((size_t)(rowbase + r) * 16 + q * 4);
    O4[0] = e0; O4[1] = e1; O4[2] = e2; O4[3] = e3;
    float ss = e0.x * e0.x + e0.y * e0.y + e0.z * e0.z + e0.w * e0.w
             + e1.x * e1.x + e1.y * e1.y + e1.z * e1.z + e1.w * e1.w
             + e2.x * e2.x + e2.y * e2.y + e2.z * e2.z + e2.w * e2.w
             + e3.x * e3.x + e3.y * e3.y + e3.z * e3.z + e3.w * e3.w;
    ss += __shfl_xor(ss, 1);
    ss += __shfl_xor(ss, 2);
    if (q == 0) lt = sxl[r] + ss - 2.f * md;
  }
#pragma unroll
  for (int off = 1; off < 64; off <<= 1) lt += __shfl_xor(lt, off);
  if (lane == 0) wls[w] = lt;
  __syncthreads();
  if (t == 0) {
    float s = 0.f;
#pragma unroll
    for (int i = 0; i < 8; ++i) s += wls[i];
    partial[bid] = s * (1.25f / 256.f);
  }
}

__global__ __launch_bounds__(256) void vq_loss(
    const float* __restrict__ partial, float* __restrict__ lossp) {
  __shared__ float wsum[4];
  float s = partial[threadIdx.x] + partial[threadIdx.x + 256];
#pragma unroll
  for (int off = 1; off < 64; off <<= 1) s += __shfl_xor(s, off);
  if ((threadIdx.x & 63) == 0) wsum[threadIdx.x >> 6] = s;
  __syncthreads();
  if (threadIdx.x == 0) lossp[0] = wsum[0] + wsum[1] + wsum[2] + wsum[3];
}

extern "C" void kernel_launch(void* const* d_in, const int* in_sizes, int n_in,
                              void* d_out, int out_size, void* d_ws, size_t ws_size,
                              hipStream_t stream) {
  const float* X = (const float*)d_in[0];   // latents [256,16384] -> [65536,64]
  const float* E = (const float*)d_in[1];   // emb [1024,64]
  float* out = (float*)d_out;
  float* loss = out + (size_t)NROWS * 64;   // d_out[4194304]

  char* ws = (char*)d_ws;
  bf16x8* img    = (bf16x8*)ws;              // [8192] frag image, 128KB
  float* partial = (float*)(ws + 131072);    // [512]

  econv<<<dim3(32), dim3(256), 0, stream>>>(E, img);
  vq_main<<<dim3(GRID), dim3(THREADS), 0, stream>>>(X, E, img, out, partial);
  vq_loss<<<dim3(1), dim3(256), 0, stream>>>(partial, loss);
}

// Round 13
// 42.480 us; speedup vs baseline: 1.6073x; 1.6073x over previous
//
#include <hip/hip_runtime.h>

// VectorQuantizer, round 13: round-12 structure, NO occupancy annotation.
// Empirical law (rounds 4,5,10,11,12): any 4-waves/EU request caps VGPR=64
// -> spill. (256,2) allowed 132 regs. m69: HW gives 4 waves/SIMD whenever
// VGPR<=128 NATURALLY. So: lean kernel (~85-100 live), __launch_bounds__
// declares block size only, allocator free, HW picks occupancy.
// econv:  E fp32 -> img[8192] bf16x8 A-frags ordered ((w*8+tl)*2+s)*64+lane
//         (vq_main loads A-frags as plain coalesced dwordx4, 1KB/instr, L2-hot).
// vq_main: grid 512 x 512 thr (8 waves, 128 rows/block). Wave owns a 128-code
//         strip in 2 passes of 4 tiles (ea[4][2] = 32 VGPRs). X staged once in
//         16KB swizzled LDS; inner loop: 2 ds_read_b128 (1-rowgroup prefetch)
//         + 8 MFMA 16x16x32 (4 indep chains) + 4 SCORE4 per rowgroup.
//         Epilogue: strip-key merge via LDS, exact fp32 E gather, on-the-fly
//         ||e||^2, per-block loss partial, zero atomics.
// vq_loss: 1 block sums 512 partials.

#define NROWS 65536
#define THREADS 512
#define GRID 512

using bf16x8 = __attribute__((ext_vector_type(8))) short;
using f32x4 = __attribute__((ext_vector_type(4))) float;

__device__ __forceinline__ short f2bf(float f) {  // fp32 -> bf16 RNE
  unsigned u = __float_as_uint(f);
  u += 0x7FFFu + ((u >> 16) & 1u);
  return (short)(u >> 16);
}

#define MFMA16(A, B, C) __builtin_amdgcn_mfma_f32_16x16x32_bf16((A), (B), (C), 0, 0, 0)

// kb bits (multiples of 4, <1024) disjoint from reg bits {0,1}; low 10
// mantissa bits carry k. v_and_or + max3-shaped tree.
#define SCORE4(Q, KB, KEY)                                                  \
  {                                                                         \
    const float v0 = __uint_as_float((__float_as_uint(Q[0]) & 0xFFFFFC00u) | (KB));       \
    const float v1 = __uint_as_float((__float_as_uint(Q[1]) & 0xFFFFFC00u) | ((KB) + 1)); \
    const float v2 = __uint_as_float((__float_as_uint(Q[2]) & 0xFFFFFC00u) | ((KB) + 2)); \
    const float v3 = __uint_as_float((__float_as_uint(Q[3]) & 0xFFFFFC00u) | ((KB) + 3)); \
    const float tt = fmaxf(fmaxf(v0, v1), v2);                              \
    KEY = fmaxf(fmaxf(KEY, tt), v3);                                        \
  }

// ---- E fp32 -> fragment-ordered bf16 image (once per launch) ----
__global__ __launch_bounds__(256) void econv(
    const float* __restrict__ E, bf16x8* __restrict__ img) {
  const int f = (int)blockIdx.x * 256 + threadIdx.x;  // 0..8191
  const int lane = f & 63;
  const int s = (f >> 6) & 1;
  const int tl = (f >> 7) & 7;
  const int w = f >> 10;
  const int code = w * 128 + tl * 16 + (lane & 15);
  const int fo = code * 16 + s * 8 + (lane >> 4) * 2;  // float4 units
  const float4* E4 = (const float4*)E;
  const float4 a = E4[fo];
  const float4 b = E4[fo + 1];
  bf16x8 v;
  v[0] = f2bf(a.x); v[1] = f2bf(a.y); v[2] = f2bf(a.z); v[3] = f2bf(a.w);
  v[4] = f2bf(b.x); v[5] = f2bf(b.y); v[6] = f2bf(b.z); v[7] = f2bf(b.w);
  img[f] = v;
}

__global__ __launch_bounds__(THREADS) void vq_main(
    const float* __restrict__ X, const float* __restrict__ E,
    const bf16x8* __restrict__ img, float* __restrict__ out,
    float* __restrict__ partial) {
  __shared__ short xt[128 * 64];    // 16KB bf16 X-tile, XOR-swizzled
  __shared__ float sxl[128];        // ||x||^2 per row
  __shared__ float lkeys[8][128];   // per-wave strip keys for merge
  __shared__ float wls[8];

  const int t = threadIdx.x;
  const int bid = (int)blockIdx.x;
  const int lane = t & 63;
  const int w = t >> 6;
  const int lo16 = lane & 15;
  const int khi = lane >> 4;        // 0..3
  const int rowbase = bid * 128;

  // ---- stage X: thread -> (row r = t>>2, quarter q = t&3), 16 floats ----
  {
    const int r = t >> 2, q = t & 3;
    const float4* X4 = (const float4*)X + ((size_t)(rowbase + r) * 16 + q * 4);
    const float4 a = X4[0], b = X4[1], c = X4[2], d = X4[3];
    float s = a.x * a.x + a.y * a.y + a.z * a.z + a.w * a.w
            + b.x * b.x + b.y * b.y + b.z * b.z + b.w * b.w
            + c.x * c.x + c.y * c.y + c.z * c.z + c.w * c.w
            + d.x * d.x + d.y * d.y + d.z * d.z + d.w * d.w;
    s += __shfl_xor(s, 1);
    s += __shfl_xor(s, 2);
    if (q == 0) sxl[r] = s;
    bf16x8 v, u;
    v[0] = f2bf(a.x); v[1] = f2bf(a.y); v[2] = f2bf(a.z); v[3] = f2bf(a.w);
    v[4] = f2bf(b.x); v[5] = f2bf(b.y); v[6] = f2bf(b.z); v[7] = f2bf(b.w);
    u[0] = f2bf(c.x); u[1] = f2bf(c.y); u[2] = f2bf(c.z); u[3] = f2bf(c.w);
    u[4] = f2bf(d.x); u[5] = f2bf(d.y); u[6] = f2bf(d.z); u[7] = f2bf(d.w);
    const int so = r * 64 + q * 16;
    const int sw = (r & 7) << 3;    // XOR swizzle (shorts), bits 3..5
    *(bf16x8*)&xt[so ^ sw] = v;
    *(bf16x8*)&xt[(so + 8) ^ sw] = u;
  }
  __syncthreads();

  // ---- K-loop: 2 passes of 4 code-tiles; A-frags loaded coalesced from the
  //      fragment-ordered image (no fp32 temps), B from LDS w/ 1-rg prefetch ----
  const int bsw = (lo16 & 7) << 3;
  float key[8];
#pragma unroll
  for (int rg = 0; rg < 8; ++rg) key[rg] = -INFINITY;
  const f32x4 z = {};
  bf16x8 b0, b1, n0, n1;

#define READB(B0, B1, RG)                                                   \
  {                                                                         \
    const int ro = ((RG) * 16 + lo16) * 64 + khi * 8;                       \
    B0 = *(const bf16x8*)&xt[ro ^ bsw];                                     \
    B1 = *(const bf16x8*)&xt[(ro + 32) ^ bsw];                              \
  }

#pragma unroll
  for (int pass = 0; pass < 2; ++pass) {
    bf16x8 ea[4][2];
    {
      const bf16x8* ib = img + ((w * 8 + pass * 4) * 2) * 64 + lane;
#pragma unroll
      for (int tl = 0; tl < 4; ++tl) {
        ea[tl][0] = ib[(2 * tl) * 64];
        ea[tl][1] = ib[(2 * tl + 1) * 64];
      }
    }
    const unsigned kpb = (unsigned)(w * 128 + pass * 64 + khi * 4);
    READB(b0, b1, 0)
#pragma unroll
    for (int rg = 0; rg < 8; ++rg) {
      if (rg < 7) READB(n0, n1, rg + 1)
      float kk = key[rg];
#pragma unroll
      for (int tl = 0; tl < 4; ++tl) {
        f32x4 q = MFMA16(ea[tl][0], b0, z);
        q = MFMA16(ea[tl][1], b1, q);
        SCORE4(q, kpb + (unsigned)(tl * 16), kk)
      }
      key[rg] = kk;
      b0 = n0; b1 = n1;
    }
  }
#undef READB

  // ---- reduce khi groups (same row, disjoint codes), publish strip keys ----
#pragma unroll
  for (int rg = 0; rg < 8; ++rg) {
    float kk = key[rg];
    kk = fmaxf(kk, __shfl_xor(kk, 16));
    kk = fmaxf(kk, __shfl_xor(kk, 32));
    if (khi == 0) lkeys[w][rg * 16 + lo16] = kk;
  }
  __syncthreads();

  // ---- merge 8 strips, gather EXACT fp32 E row, loss term ----
  float lt = 0.f;
  {
    const int r = t >> 2, q = t & 3;
    float m = lkeys[0][r];
    m = fmaxf(m, lkeys[1][r]); m = fmaxf(m, lkeys[2][r]);
    m = fmaxf(m, lkeys[3][r]); m = fmaxf(m, lkeys[4][r]);
    m = fmaxf(m, lkeys[5][r]); m = fmaxf(m, lkeys[6][r]);
    m = fmaxf(m, lkeys[7][r]);
    const unsigned kbu = __float_as_uint(m);
    const int k = (int)(kbu & 1023u);
    const float md = __uint_as_float(kbu & 0xFFFFFC00u);
    const float4* Ek = (const float4*)E + ((size_t)k * 16 + q * 4);
    const float4 e0 = Ek[0], e1 = Ek[1], e2 = Ek[2], e3 = Ek[3];
    float4* O4 = (float4*)out + ((size_t)(rowbase + r) * 16 + q * 4);
    O4[0] = e0; O4[1] = e1; O4[2] = e2; O4[3] = e3;
    float ss = e0.x * e0.x + e0.y * e0.y + e0.z * e0.z + e0.w * e0.w
             + e1.x * e1.x + e1.y * e1.y + e1.z * e1.z + e1.w * e1.w
             + e2.x * e2.x + e2.y * e2.y + e2.z * e2.z + e2.w * e2.w
             + e3.x * e3.x + e3.y * e3.y + e3.z * e3.z + e3.w * e3.w;
    ss += __shfl_xor(ss, 1);
    ss += __shfl_xor(ss, 2);
    if (q == 0) lt = sxl[r] + ss - 2.f * md;
  }
#pragma unroll
  for (int off = 1; off < 64; off <<= 1) lt += __shfl_xor(lt, off);
  if (lane == 0) wls[w] = lt;
  __syncthreads();
  if (t == 0) {
    float s = 0.f;
#pragma unroll
    for (int i = 0; i < 8; ++i) s += wls[i];
    partial[bid] = s * (1.25f / 256.f);
  }
}

__global__ __launch_bounds__(256) void vq_loss(
    const float* __restrict__ partial, float* __restrict__ lossp) {
  __shared__ float wsum[4];
  float s = partial[threadIdx.x] + partial[threadIdx.x + 256];
#pragma unroll
  for (int off = 1; off < 64; off <<= 1) s += __shfl_xor(s, off);
  if ((threadIdx.x & 63) == 0) wsum[threadIdx.x >> 6] = s;
  __syncthreads();
  if (threadIdx.x == 0) lossp[0] = wsum[0] + wsum[1] + wsum[2] + wsum[3];
}

extern "C" void kernel_launch(void* const* d_in, const int* in_sizes, int n_in,
                              void* d_out, int out_size, void* d_ws, size_t ws_size,
                              hipStream_t stream) {
  const float* X = (const float*)d_in[0];   // latents [256,16384] -> [65536,64]
  const float* E = (const float*)d_in[1];   // emb [1024,64]
  float* out = (float*)d_out;
  float* loss = out + (size_t)NROWS * 64;   // d_out[4194304]

  char* ws = (char*)d_ws;
  bf16x8* img    = (bf16x8*)ws;              // [8192] frag image, 128KB
  float* partial = (float*)(ws + 131072);    // [512]

  econv<<<dim3(32), dim3(256), 0, stream>>>(E, img);
  vq_main<<<dim3(GRID), dim3(THREADS), 0, stream>>>(X, E, img, out, partial);
  vq_loss<<<dim3(1), dim3(256), 0, stream>>>(partial, loss);
}

// Round 14
// 36.250 us; speedup vs baseline: 1.8835x; 1.1719x over previous
//
#include <hip/hip_runtime.h>

// VectorQuantizer, round 14: round 7 EXACTLY, minus the register cap.
// Round 7's (256,4) capped VGPR=64 -> 69MB spill (its 31us). Demand ~95 regs.
// With plain __launch_bounds__(256), allocation should land <=128 and the HW
// grants 16 waves/CU (m69 law) = 4 waves/SIMD, 4 blocks/CU (36.9KB LDS).
// Also: staging loop NOT unrolled (keeps prologue peak pressure low).
// K1 (vq_part): 4-way K-split argmax via bf16 MFMA 16x16x32; grid 1024 =
//   256 rowgroups x 4 chunks; 256 thr; 64 rows/wave as 4 colgroups of 16.
// K2 (vq_fin): combine 4 partials, gather emb fp32 -> out, per-block loss
//   partial (no single-address atomics: round 2 showed those cost 212us).
// K3 (vq_loss): 1 block sums 4096 partials -> loss scalar.

#define NROWS 65536
#define DDIM  64
#define KCB   1024
#define NCHUNK 4
#define KCHUNK 256
#define ROWSTRIDE 72  // shorts per LDS E-row: 144B; measured 0 bank conflicts
#define NFIN_BLOCKS (NROWS * 16 / 256)   // 4096

using bf16x8 = __attribute__((ext_vector_type(8))) short;
using f32x4 = __attribute__((ext_vector_type(4))) float;

__device__ __forceinline__ short f2bf(float f) {  // fp32 -> bf16 RNE
  unsigned u = __float_as_uint(f);
  u += 0x7FFFu + ((u >> 16) & 1u);
  return (short)(u >> 16);
}

#define MFMA16(A, B, C) __builtin_amdgcn_mfma_f32_16x16x32_bf16((A), (B), (C), 0, 0, 0)

__global__ __launch_bounds__(256) void vq_part(
    const float* __restrict__ X, const float* __restrict__ E,
    float* __restrict__ pk, float* __restrict__ sx) {
  __shared__ short ebf[KCHUNK * ROWSTRIDE];  // 36864 B -> 4 blocks/CU

  const int t = threadIdx.x;
  const int chunk = (int)blockIdx.x & (NCHUNK - 1);
  const int rowgroup = (int)blockIdx.x >> 2;

  // ---- stage this chunk's 256 E rows as bf16 (1 thread per row);
  //      NO unroll: keeps prologue register peak small ----
  {
    const float4* E4 = (const float4*)E;
    const int krr = (t + rowgroup * 2) & (KCHUNK - 1);  // stagger across blocks
    const int kg = chunk * KCHUNK + krr;
    for (int g = 0; g < 8; ++g) {
      float4 a = E4[kg * 16 + 2 * g];
      float4 b = E4[kg * 16 + 2 * g + 1];
      bf16x8 v;
      v[0] = f2bf(a.x); v[1] = f2bf(a.y); v[2] = f2bf(a.z); v[3] = f2bf(a.w);
      v[4] = f2bf(b.x); v[5] = f2bf(b.y); v[6] = f2bf(b.z); v[7] = f2bf(b.w);
      *(bf16x8*)&ebf[krr * ROWSTRIDE + g * 8] = v;
    }
  }
  __syncthreads();

  const int lane = t & 63;
  const int w = t >> 6;
  const int lo16 = lane & 15;   // A: E-row within tile / B: x-row within colgroup / C: col
  const int khi = lane >> 4;    // k-block selector (0..3)
  const int rowbase = rowgroup * 256 + w * 64;  // 64 rows per wave

  // ---- X fragments: 4 col-groups of 16 rows, 2 k-slices each.
  //      B-frag 16x16x32: col(x-row)=lane&15, k=(lane>>4)*8+j ----
  bf16x8 xf00, xf01, xf10, xf11, xf20, xf21, xf30, xf31;
  float sx0, sx1, sx2, sx3;
  {
    const float4* X4 = (const float4*)X;
#define LOADX(XF0, XF1, SX, CG)                                             \
    {                                                                       \
      const int rg = rowbase + 16 * (CG) + lo16;                            \
      float4 a = X4[rg * 16 + khi * 2];                                     \
      float4 b = X4[rg * 16 + khi * 2 + 1];                                 \
      float4 c = X4[rg * 16 + 8 + khi * 2];                                 \
      float4 d = X4[rg * 16 + 8 + khi * 2 + 1];                             \
      SX = a.x * a.x + a.y * a.y + a.z * a.z + a.w * a.w                    \
         + b.x * b.x + b.y * b.y + b.z * b.z + b.w * b.w                    \
         + c.x * c.x + c.y * c.y + c.z * c.z + c.w * c.w                    \
         + d.x * d.x + d.y * d.y + d.z * d.z + d.w * d.w;                   \
      bf16x8 v, u;                                                          \
      v[0] = f2bf(a.x); v[1] = f2bf(a.y); v[2] = f2bf(a.z); v[3] = f2bf(a.w); \
      v[4] = f2bf(b.x); v[5] = f2bf(b.y); v[6] = f2bf(b.z); v[7] = f2bf(b.w); \
      u[0] = f2bf(c.x); u[1] = f2bf(c.y); u[2] = f2bf(c.z); u[3] = f2bf(c.w); \
      u[4] = f2bf(d.x); u[5] = f2bf(d.y); u[6] = f2bf(d.z); u[7] = f2bf(d.w); \
      XF0 = v; XF1 = u;                                                     \
    }
    LOADX(xf00, xf01, sx0, 0)
    LOADX(xf10, xf11, sx1, 1)
    LOADX(xf20, xf21, sx2, 2)
    LOADX(xf30, xf31, sx3, 3)
#undef LOADX
  }

  // ---- 16 tiles of 16 codes. A-frag 16x16x32: row(code)=lane&15,
  //      k=(lane>>4)*8+j, slice s at +32 shorts. One b128 read per slice.
  //      C layout: col(x-row)=lane&15, code=(lane>>4)*4+reg. ----
  const unsigned kbl = (unsigned)(chunk * KCHUNK + khi * 4);
  const int khi8 = khi * 8;
  float key0 = -INFINITY, key1 = -INFINITY, key2 = -INFINITY, key3 = -INFINITY;
  bf16x8 afA0, afA1, afB0, afB1;
  const f32x4 z = {};

#define READA(A0, A1, TILE)                                                 \
  {                                                                         \
    const short* ap = ebf + ((TILE) * 16 + lo16) * ROWSTRIDE + khi8;        \
    A0 = *(const bf16x8*)ap;                                                \
    A1 = *(const bf16x8*)(ap + 32);                                         \
  }
  // kb bits (multiples of 4, <1024) are disjoint from reg bits {0,1};
  // mask clears low 10 mantissa bits. max3-shaped tree.
#define SCORE4(Q, KB, KEY)                                                  \
  {                                                                         \
    const float v0 = __uint_as_float((__float_as_uint(Q[0]) & 0xFFFFFC00u) | (KB));       \
    const float v1 = __uint_as_float((__float_as_uint(Q[1]) & 0xFFFFFC00u) | ((KB) + 1)); \
    const float v2 = __uint_as_float((__float_as_uint(Q[2]) & 0xFFFFFC00u) | ((KB) + 2)); \
    const float v3 = __uint_as_float((__float_as_uint(Q[3]) & 0xFFFFFC00u) | ((KB) + 3)); \
    const float tt = fmaxf(fmaxf(v0, v1), v2);                              \
    KEY = fmaxf(fmaxf(KEY, tt), v3);                                        \
  }
#define TILE_STEP(A0, A1, TILE)                                             \
  {                                                                         \
    f32x4 q0 = MFMA16(A0, xf00, z), q1 = MFMA16(A0, xf10, z);               \
    f32x4 q2 = MFMA16(A0, xf20, z), q3 = MFMA16(A0, xf30, z);               \
    q0 = MFMA16(A1, xf01, q0); q1 = MFMA16(A1, xf11, q1);                   \
    q2 = MFMA16(A1, xf21, q2); q3 = MFMA16(A1, xf31, q3);                   \
    const unsigned kb = kbl + (TILE) * 16;                                  \
    SCORE4(q0, kb, key0) SCORE4(q1, kb, key1)                               \
    SCORE4(q2, kb, key2) SCORE4(q3, kb, key3)                               \
  }

  READA(afA0, afA1, 0)
#pragma unroll
  for (int kp = 0; kp < 8; ++kp) {
    READA(afB0, afB1, 2 * kp + 1)
    TILE_STEP(afA0, afA1, 2 * kp)
    if (kp < 7) READA(afA0, afA1, 2 * kp + 2)
    TILE_STEP(afB0, afB1, 2 * kp + 1)
  }
#undef TILE_STEP
#undef SCORE4
#undef READA

  // ---- reduce across the 4 lane-groups sharing each x-row (lane&15) ----
  key0 = fmaxf(key0, __shfl_xor(key0, 16)); key0 = fmaxf(key0, __shfl_xor(key0, 32));
  key1 = fmaxf(key1, __shfl_xor(key1, 16)); key1 = fmaxf(key1, __shfl_xor(key1, 32));
  key2 = fmaxf(key2, __shfl_xor(key2, 16)); key2 = fmaxf(key2, __shfl_xor(key2, 32));
  key3 = fmaxf(key3, __shfl_xor(key3, 16)); key3 = fmaxf(key3, __shfl_xor(key3, 32));
  sx0 += __shfl_xor(sx0, 16); sx0 += __shfl_xor(sx0, 32);
  sx1 += __shfl_xor(sx1, 16); sx1 += __shfl_xor(sx1, 32);
  sx2 += __shfl_xor(sx2, 16); sx2 += __shfl_xor(sx2, 32);
  sx3 += __shfl_xor(sx3, 16); sx3 += __shfl_xor(sx3, 32);

  // lane's colgroup = khi; select that key -> one coalesced 64-lane store
  const float kv = (khi == 0) ? key0 : (khi == 1) ? key1 : (khi == 2) ? key2 : key3;
  pk[chunk * NROWS + rowbase + lane] = kv;
  if (chunk == 0) {
    const float sv = (khi == 0) ? sx0 : (khi == 1) ? sx1 : (khi == 2) ? sx2 : sx3;
    sx[rowbase + lane] = sv;
  }
}

__global__ __launch_bounds__(256) void vq_fin(
    const float* __restrict__ E, const float* __restrict__ pk,
    const float* __restrict__ sx, float* __restrict__ out,
    float* __restrict__ partial) {
  __shared__ float wsum[4];
  const int t = (int)blockIdx.x * 256 + threadIdx.x;  // 1M threads
  const int row = t >> 4;
  const int col = t & 15;

  // lanes col=0..3 each load one chunk partial; 16-lane xor-max broadcast
  float key = (col < NCHUNK) ? pk[col * NROWS + row] : -INFINITY;
  key = fmaxf(key, __shfl_xor(key, 1));
  key = fmaxf(key, __shfl_xor(key, 2));
  key = fmaxf(key, __shfl_xor(key, 4));
  key = fmaxf(key, __shfl_xor(key, 8));

  const unsigned kb = __float_as_uint(key);
  const int k = (int)(kb & 1023u);
  const float md = __uint_as_float(kb & 0xFFFFFC00u);

  const float4 e = ((const float4*)E)[k * 16 + col];
  ((float4*)out)[(size_t)row * 16 + col] = e;

  float ss = e.x * e.x + e.y * e.y + e.z * e.z + e.w * e.w;
  ss += __shfl_xor(ss, 1);
  ss += __shfl_xor(ss, 2);
  ss += __shfl_xor(ss, 4);
  ss += __shfl_xor(ss, 8);

  // per-block loss partial: wave shfl -> LDS -> thread 0 (ZERO atomics)
  float lr = (col == 0) ? (sx[row] + ss - 2.f * md) : 0.f;
  lr += __shfl_xor(lr, 16);
  lr += __shfl_xor(lr, 32);
  if ((threadIdx.x & 63) == 0) wsum[threadIdx.x >> 6] = lr;
  __syncthreads();
  if (threadIdx.x == 0)
    partial[blockIdx.x] = (wsum[0] + wsum[1] + wsum[2] + wsum[3]) * (1.25f / 256.f);
}

__global__ __launch_bounds__(256) void vq_loss(
    const float* __restrict__ partial, float* __restrict__ lossp) {
  __shared__ float wsum[4];
  float s = 0.f;
#pragma unroll
  for (int i = 0; i < NFIN_BLOCKS / 256; ++i) s += partial[i * 256 + threadIdx.x];
#pragma unroll
  for (int off = 1; off < 64; off <<= 1) s += __shfl_xor(s, off);
  if ((threadIdx.x & 63) == 0) wsum[threadIdx.x >> 6] = s;
  __syncthreads();
  if (threadIdx.x == 0) lossp[0] = wsum[0] + wsum[1] + wsum[2] + wsum[3];
}

extern "C" void kernel_launch(void* const* d_in, const int* in_sizes, int n_in,
                              void* d_out, int out_size, void* d_ws, size_t ws_size,
                              hipStream_t stream) {
  const float* X = (const float*)d_in[0];   // latents [256,16384] -> [65536,64]
  const float* E = (const float*)d_in[1];   // emb [1024,64]
  float* out = (float*)d_out;
  float* loss = out + (size_t)NROWS * DDIM;  // d_out[4194304]
  float* ws = (float*)d_ws;
  float* pk = ws;                             // [4*NROWS]
  float* sxb = ws + NCHUNK * NROWS;           // [NROWS]
  float* partial = ws + (NCHUNK + 1) * NROWS; // [4096]

  vq_part<<<dim3(256 * NCHUNK), dim3(256), 0, stream>>>(X, E, pk, sxb);
  vq_fin<<<dim3(NFIN_BLOCKS), dim3(256), 0, stream>>>(E, pk, sxb, out, partial);
  vq_loss<<<dim3(1), dim3(256), 0, stream>>>(partial, loss);
}

// Round 15
// 27.181 us; speedup vs baseline: 2.5120x; 1.3337x over previous
//
#include <hip/hip_runtime.h>

// VectorQuantizer, round 15: round 9 VERBATIM + one change: A-frag prefetch
// deepened from 1 tile-pair to 2 (4 named buffers, 8 b128 in flight,
// prefetch distance ~180cy > ~120cy ds_read latency). Round 9 = best (26.9us);
// rounds 10-14 all regressed chasing occupancy. 128KB LDS caps this kernel at
// 1 block/CU = 2 waves/SIMD REGARDLESS of VGPR -> compiler budget is 256 regs
// (why round 9 never spilled at (512) bounds while 21.5KB-LDS variants got
// capped at 128) -> +32 prefetch regs are free.
// econv:  E fp32 -> PRE-SWIZZLED bf16 image (128KB) + sel[k] in ws.
// vq_main: grid 256 x 512 thr (8 waves, 32 rows/wave), full K=1024 in LDS.
// vq_loss: 1 block sums 256 partials.

#define NROWS 65536
#define DDIM  64
#define KCB   1024
#define THREADS 512
#define GRID 256          // 1 block/CU, 128KB LDS, 2 waves/SIMD

using bf16x8 = __attribute__((ext_vector_type(8))) short;
using f32x4 = __attribute__((ext_vector_type(4))) float;

__device__ __forceinline__ short f2bf(float f) {  // fp32 -> bf16 RNE
  unsigned u = __float_as_uint(f);
  u += 0x7FFFu + ((u >> 16) & 1u);
  return (short)(u >> 16);
}

#define MFMA16(A, B, C) __builtin_amdgcn_mfma_f32_16x16x32_bf16((A), (B), (C), 0, 0, 0)

// kb bits (multiples of 4, <1024) disjoint from reg bits {0,1}; low 10
// mantissa bits carry k. max3-shaped tree.
#define SCORE4(Q, KB, KEY)                                                  \
  {                                                                         \
    const float v0 = __uint_as_float((__float_as_uint(Q[0]) & 0xFFFFFC00u) | (KB));       \
    const float v1 = __uint_as_float((__float_as_uint(Q[1]) & 0xFFFFFC00u) | ((KB) + 1)); \
    const float v2 = __uint_as_float((__float_as_uint(Q[2]) & 0xFFFFFC00u) | ((KB) + 2)); \
    const float v3 = __uint_as_float((__float_as_uint(Q[3]) & 0xFFFFFC00u) | ((KB) + 3)); \
    const float tt = fmaxf(fmaxf(v0, v1), v2);                              \
    KEY = fmaxf(fmaxf(KEY, tt), v3);                                        \
  }

// ---- E fp32 -> swizzled bf16 image + sel (once per launch) ----
__global__ __launch_bounds__(256) void econv(
    const float* __restrict__ E, short* __restrict__ ebf_g,
    float* __restrict__ sel_g) {
  const int k = (int)blockIdx.x * 256 + threadIdx.x;  // 1024 threads total
  const float4* E4 = (const float4*)E;
  const int swz = (k & 7) << 3;
  float s = 0.f;
#pragma unroll
  for (int g = 0; g < 8; ++g) {
    float4 a = E4[k * 16 + 2 * g];
    float4 b = E4[k * 16 + 2 * g + 1];
    s += a.x * a.x + a.y * a.y + a.z * a.z + a.w * a.w;
    s += b.x * b.x + b.y * b.y + b.z * b.z + b.w * b.w;
    bf16x8 v;
    v[0] = f2bf(a.x); v[1] = f2bf(a.y); v[2] = f2bf(a.z); v[3] = f2bf(a.w);
    v[4] = f2bf(b.x); v[5] = f2bf(b.y); v[6] = f2bf(b.z); v[7] = f2bf(b.w);
    *(bf16x8*)&ebf_g[k * 64 + ((g << 3) ^ swz)] = v;
  }
  sel_g[k] = s;
}

__global__ __launch_bounds__(THREADS, 2) void vq_main(
    const float* __restrict__ X, const short* __restrict__ ebf_g,
    const float* __restrict__ sel_g, float* __restrict__ out,
    float* __restrict__ partial) {
  __shared__ short ebf[KCB * 64];   // 131072 B, pre-swizzled image
  __shared__ float wls[8];

  const int t = threadIdx.x;
  const int bid = (int)blockIdx.x;

  // ---- stage: linear 128KB copy of the pre-swizzled image ----
  {
    const bf16x8* ws8 = (const bf16x8*)ebf_g;
    bf16x8* lds8 = (bf16x8*)ebf;
#pragma unroll
    for (int it = 0; it < 16; ++it) lds8[it * THREADS + t] = ws8[it * THREADS + t];
  }

  const int lane = t & 63;
  const int w = t >> 6;
  const int lo16 = lane & 15;
  const int khi = lane >> 4;            // 0..3
  const int rowbase = bid * 256 + w * 32;

  // ---- X fragments (loads overlap the staging barrier):
  //      B-frag: col(x-row)=lane&15, k=(lane>>4)*8+j; slice s: d=s*32+khi*8+j ----
  bf16x8 xf00, xf01, xf10, xf11;
  float sx0, sx1;
  {
    const float4* X4 = (const float4*)X;
#define LOADX(XF0, XF1, SX, CG)                                             \
    {                                                                       \
      const int rg = rowbase + 16 * (CG) + lo16;                            \
      float4 a = X4[rg * 16 + khi * 2];                                     \
      float4 b = X4[rg * 16 + khi * 2 + 1];                                 \
      float4 c = X4[rg * 16 + 8 + khi * 2];                                 \
      float4 d = X4[rg * 16 + 8 + khi * 2 + 1];                             \
      SX = a.x * a.x + a.y * a.y + a.z * a.z + a.w * a.w                    \
         + b.x * b.x + b.y * b.y + b.z * b.z + b.w * b.w                    \
         + c.x * c.x + c.y * c.y + c.z * c.z + c.w * c.w                    \
         + d.x * d.x + d.y * d.y + d.z * d.z + d.w * d.w;                   \
      bf16x8 v, u;                                                          \
      v[0] = f2bf(a.x); v[1] = f2bf(a.y); v[2] = f2bf(a.z); v[3] = f2bf(a.w); \
      v[4] = f2bf(b.x); v[5] = f2bf(b.y); v[6] = f2bf(b.z); v[7] = f2bf(b.w); \
      u[0] = f2bf(c.x); u[1] = f2bf(c.y); u[2] = f2bf(c.z); u[3] = f2bf(c.w); \
      u[4] = f2bf(d.x); u[5] = f2bf(d.y); u[6] = f2bf(d.z); u[7] = f2bf(d.w); \
      XF0 = v; XF1 = u;                                                     \
    }
    LOADX(xf00, xf01, sx0, 0)
    LOADX(xf10, xf11, sx1, 1)
#undef LOADX
  }
  __syncthreads();

  // ---- 64 tiles of 16 codes, in pairs; 2-PAIR-DEEP prefetch (8 b128 in
  //      flight, distance ~2 STEP2s > ds_read latency).
  //      A-frag: row(code)=lane&15, k=(lane>>4)*8+j; slice s at short
  //      offset (s*4+khi ^ (row&7))<<3.  C: col=lane&15, code=4*khi'+reg. ----
  const int swz0 = (khi ^ (lo16 & 7)) << 3;
  const int swz1 = ((4 + khi) ^ (lo16 & 7)) << 3;
  const unsigned kblane = (unsigned)(khi * 4);
  float key0 = -INFINITY, key1 = -INFINITY;
  bf16x8 aA0, aA1, aA2, aA3, aB0, aB1, aB2, aB3;
  bf16x8 aC0, aC1, aC2, aC3, aD0, aD1, aD2, aD3;
  const f32x4 z = {};

#define READ2(P0, P1, P2, P3, TB)                                           \
  {                                                                         \
    const short* ap = ebf + ((TB) * 16 + lo16) * 64;                        \
    P0 = *(const bf16x8*)(ap + swz0);                                       \
    P1 = *(const bf16x8*)(ap + swz1);                                       \
    const short* ap2 = ap + 1024;                                           \
    P2 = *(const bf16x8*)(ap2 + swz0);                                      \
    P3 = *(const bf16x8*)(ap2 + swz1);                                      \
  }
#define STEP2(P0, P1, P2, P3, TB)                                           \
  {                                                                         \
    f32x4 q0 = MFMA16(P0, xf00, z), q1 = MFMA16(P0, xf10, z);               \
    f32x4 r0 = MFMA16(P2, xf00, z), r1 = MFMA16(P2, xf10, z);               \
    q0 = MFMA16(P1, xf01, q0); q1 = MFMA16(P1, xf11, q1);                   \
    r0 = MFMA16(P3, xf01, r0); r1 = MFMA16(P3, xf11, r1);                   \
    const unsigned kb0 = kblane + (TB) * 16;                                \
    const unsigned kb1 = kb0 + 16;                                          \
    SCORE4(q0, kb0, key0) SCORE4(q1, kb0, key1)                             \
    SCORE4(r0, kb1, key0) SCORE4(r1, kb1, key1)                             \
  }

  READ2(aA0, aA1, aA2, aA3, 0)
  READ2(aB0, aB1, aB2, aB3, 2)
#pragma unroll
  for (int kp = 0; kp < 16; ++kp) {
    if (kp < 15) {
      READ2(aC0, aC1, aC2, aC3, 4 * kp + 4)
      READ2(aD0, aD1, aD2, aD3, 4 * kp + 6)
    }
    STEP2(aA0, aA1, aA2, aA3, 4 * kp)
    STEP2(aB0, aB1, aB2, aB3, 4 * kp + 2)
    aA0 = aC0; aA1 = aC1; aA2 = aC2; aA3 = aC3;
    aB0 = aD0; aB1 = aD1; aB2 = aD2; aB3 = aD3;
  }
#undef STEP2
#undef READ2

  // ---- reduce over the 4 khi groups sharing each x-row ----
  key0 = fmaxf(key0, __shfl_xor(key0, 16)); key0 = fmaxf(key0, __shfl_xor(key0, 32));
  key1 = fmaxf(key1, __shfl_xor(key1, 16)); key1 = fmaxf(key1, __shfl_xor(key1, 32));
  sx0 += __shfl_xor(sx0, 16); sx0 += __shfl_xor(sx0, 32);
  sx1 += __shfl_xor(sx1, 16); sx1 += __shfl_xor(sx1, 32);

  // ---- fused gather (LDS bf16 -> f32) + loss terms ----
  float lt = 0.f;
  {
    float4* O4 = (float4*)out;
#define EMIT(KEY, SX, CG)                                                   \
    {                                                                       \
      const unsigned kbu = __float_as_uint(KEY);                            \
      const int k = (int)(kbu & 1023u);                                     \
      const float md = __uint_as_float(kbu & 0xFFFFFC00u);                  \
      const int row = rowbase + 16 * (CG) + lo16;                           \
      const int esw = (k & 7) << 3;                                         \
      const short* ep = ebf + k * 64;                                       \
      const bf16x8 h0 = *(const bf16x8*)(ep + (((khi * 2) << 3) ^ esw));    \
      const bf16x8 h1 = *(const bf16x8*)(ep + (((khi * 2 + 1) << 3) ^ esw));\
      float4 o;                                                             \
      _Pragma("unroll")                                                     \
      for (int i = 0; i < 2; ++i) {                                         \
        const bf16x8 h = i ? h1 : h0;                                       \
        o.x = __uint_as_float(((unsigned)(unsigned short)h[0]) << 16);      \
        o.y = __uint_as_float(((unsigned)(unsigned short)h[1]) << 16);      \
        o.z = __uint_as_float(((unsigned)(unsigned short)h[2]) << 16);      \
        o.w = __uint_as_float(((unsigned)(unsigned short)h[3]) << 16);      \
        O4[(size_t)row * 16 + khi * 4 + 2 * i] = o;                         \
        o.x = __uint_as_float(((unsigned)(unsigned short)h[4]) << 16);      \
        o.y = __uint_as_float(((unsigned)(unsigned short)h[5]) << 16);      \
        o.z = __uint_as_float(((unsigned)(unsigned short)h[6]) << 16);      \
        o.w = __uint_as_float(((unsigned)(unsigned short)h[7]) << 16);      \
        O4[(size_t)row * 16 + khi * 4 + 2 * i + 1] = o;                     \
      }                                                                     \
      if (khi == 0) lt += SX + sel_g[k] - 2.f * md;                         \
    }
    EMIT(key0, sx0, 0)
    EMIT(key1, sx1, 1)
#undef EMIT
  }

  // ---- block loss partial (zero atomics) ----
#pragma unroll
  for (int off = 1; off < 64; off <<= 1) lt += __shfl_xor(lt, off);
  if (lane == 0) wls[w] = lt;
  __syncthreads();
  if (t == 0) {
    float s = 0.f;
#pragma unroll
    for (int i = 0; i < 8; ++i) s += wls[i];
    partial[bid] = s * (1.25f / 256.f);
  }
}

__global__ __launch_bounds__(256) void vq_loss(
    const float* __restrict__ partial, float* __restrict__ lossp) {
  __shared__ float wsum[4];
  float s = partial[threadIdx.x];
#pragma unroll
  for (int off = 1; off < 64; off <<= 1) s += __shfl_xor(s, off);
  if ((threadIdx.x & 63) == 0) wsum[threadIdx.x >> 6] = s;
  __syncthreads();
  if (threadIdx.x == 0) lossp[0] = wsum[0] + wsum[1] + wsum[2] + wsum[3];
}

extern "C" void kernel_launch(void* const* d_in, const int* in_sizes, int n_in,
                              void* d_out, int out_size, void* d_ws, size_t ws_size,
                              hipStream_t stream) {
  const float* X = (const float*)d_in[0];   // latents [256,16384] -> [65536,64]
  const float* E = (const float*)d_in[1];   // emb [1024,64]
  float* out = (float*)d_out;
  float* loss = out + (size_t)NROWS * DDIM;  // d_out[4194304]

  char* ws = (char*)d_ws;
  short* ebf_g   = (short*)ws;               // [1024*64] bf16 image, 128KB
  float* sel_g   = (float*)(ws + 131072);    // [1024]
  float* partial = (float*)(ws + 135168);    // [256]

  econv<<<dim3(4), dim3(256), 0, stream>>>(E, ebf_g, sel_g);
  vq_main<<<dim3(GRID), dim3(THREADS), 0, stream>>>(X, ebf_g, sel_g, out, partial);
  vq_loss<<<dim3(1), dim3(256), 0, stream>>>(partial, loss);
}